// Round 2
// baseline (295.532 us; speedup 1.0000x reference)
//
#include <hip/hip_runtime.h>
#include <hip/hip_bf16.h>

#define BB 4
#define TT 2048
#define DDIM 1024
#define HH 16
#define HD 64

typedef __bf16 bf16_t;
typedef __bf16 bf16x4 __attribute__((ext_vector_type(4)));
typedef __bf16 bf16x8 __attribute__((ext_vector_type(8)));
typedef float f32x4 __attribute__((ext_vector_type(4)));

#define GLOAD_LDS(gp, lp) \
    __builtin_amdgcn_global_load_lds( \
        (const __attribute__((address_space(1))) void*)(gp), \
        (__attribute__((address_space(3))) void*)(lp), 16, 0, 0)

// ---------------------------------------------------------------------------
// fp32 -> bf16 conversion, 8 elems/thread, grid-stride. n8 = n/8.
// ---------------------------------------------------------------------------
__global__ __launch_bounds__(256) void cvt_f32_bf16(
    const float* __restrict__ src, bf16_t* __restrict__ dst, size_t n8)
{
    size_t i = (size_t)blockIdx.x * blockDim.x + threadIdx.x;
    const size_t stride = (size_t)gridDim.x * blockDim.x;
    for (; i < n8; i += stride) {
        const f32x4 a = ((const f32x4*)src)[2 * i];
        const f32x4 b = ((const f32x4*)src)[2 * i + 1];
        bf16x8 v;
#pragma unroll
        for (int j = 0; j < 4; j++) { v[j] = (bf16_t)a[j]; v[4 + j] = (bf16_t)b[j]; }
        ((bf16x8*)dst)[i] = v;
    }
}

// Pack 4 fp32 weight matrices into one bf16 buffer [wq|wk|wv|wo].
__global__ __launch_bounds__(256) void cvt_wpack(
    const float* __restrict__ s0, const float* __restrict__ s1,
    const float* __restrict__ s2, const float* __restrict__ s3,
    bf16_t* __restrict__ dst)
{
    const size_t n8 = (size_t)4 * DDIM * DDIM / 8;
    size_t i = (size_t)blockIdx.x * blockDim.x + threadIdx.x;
    const size_t stride = (size_t)gridDim.x * blockDim.x;
    for (; i < n8; i += stride) {
        const int sel = (int)(i >> 17);
        const float* s = sel == 0 ? s0 : sel == 1 ? s1 : sel == 2 ? s2 : s3;
        const size_t off8 = i & ((1u << 17) - 1);
        const f32x4 a = ((const f32x4*)s)[2 * off8];
        const f32x4 b = ((const f32x4*)s)[2 * off8 + 1];
        bf16x8 v;
#pragma unroll
        for (int j = 0; j < 4; j++) { v[j] = (bf16_t)a[j]; v[4 + j] = (bf16_t)b[j]; }
        ((bf16x8*)dst)[i] = v;
    }
}

// ---------------------------------------------------------------------------
// BK=64 XOR-row staging (global_load_lds cannot scatter per lane, so the
// GLOBAL source column is permuted instead): LDS[row][c] = G[row][c ^
// ((row&1)*4)] at 8-elem chunk granularity. Fragment reads un-XOR ->
// bank-balanced (8 slots x 8 lanes) despite the 128B row stride.
// Stages 8 rows per instruction: lane -> row lane>>3, chunk lane&7.
// ---------------------------------------------------------------------------
__device__ __forceinline__ void stage8(const bf16_t* __restrict__ g, int ld,
                                       bf16_t* __restrict__ ldsbase, int lane)
{
    const int rr = lane >> 3;
    const int cc = (lane & 7) ^ ((rr & 1) << 2);
    GLOAD_LDS(&g[(size_t)rr * ld + cc * 8], ldsbase);
}

// ---------------------------------------------------------------------------
// Fused QKV GEMM v2: phase-split double-buffered 256x192 tile, BK=64,
// 512 threads (8 waves, 2M x 4N; per-wave 128x48 = acc[8][3]).
// Schedule per K-tile (T3-lite): issue ALL of tile t+1's global_load_lds
// into buf^1 at the top, then 4 phases {8 ds_read_b128 -> setprio(1) ->
// 12 MFMA -> setprio(0) -> s_barrier} on buf, then __syncthreads() (the
// only correctness-critical sync: drains vmcnt + guards buffer swap).
// Load latency hides under ~3.5 phases of MFMA instead of a naked drain
// (v1 was 1-phase: 662 TF, MfmaUtil 27%). Intra-tile raw s_barriers only
// pin the cross-wave interleave; data is landed at tile start, so any
// compiler reordering across them is still race-free.
// BN=192 -> grid (16, M/256) = 512 blocks = exactly 2 full rounds at
// 1 block/CU (112 KiB LDS); BN=256 would leave round 2 half-empty.
// Epilogue per-fragment region: Q natural / K natural / V [B,H,HD,T].
// ---------------------------------------------------------------------------
__global__ __launch_bounds__(512, 2) void gemm_qkv(
    const bf16_t* __restrict__ A, const bf16_t* __restrict__ Wqkv,
    bf16_t* __restrict__ Qo, bf16_t* __restrict__ Ko, bf16_t* __restrict__ Vto,
    int M, int K)
{
    __shared__ alignas(16) bf16_t As[2][256 * 64];
    __shared__ alignas(16) bf16_t Bs[2][192 * 64];

    const int tid  = threadIdx.x;
    const int lane = tid & 63;
    const int w    = tid >> 6;          // 0..7
    const int quad = lane >> 4;
    const int l15  = lane & 15;
    const int wm   = (w >> 2) * 128;    // 0 / 128
    const int wn   = (w & 3) * 48;      // 0 / 48 / 96 / 144
    const int tileN = blockIdx.x * 192;
    const int tileM = blockIdx.y * 256;

    const f32x4 vzero = {0.f, 0.f, 0.f, 0.f};
    f32x4 acc[8][3];
#pragma unroll
    for (int i = 0; i < 8; i++)
#pragma unroll
        for (int j = 0; j < 3; j++) acc[i][j] = vzero;

    const int par4 = (l15 & 1) << 2;     // read-side un-XOR

    // prologue: stage K-tile 0 into buf 0
#pragma unroll
    for (int q = 0; q < 4; q++) {
        const int r0 = w * 32 + q * 8;
        stage8(&A[(size_t)(tileM + r0) * K], K, &As[0][r0 * 64], lane);
    }
#pragma unroll
    for (int q = 0; q < 3; q++) {
        const int r0 = w * 24 + q * 8;
        stage8(&Wqkv[(size_t)(tileN + r0) * K], K, &Bs[0][r0 * 64], lane);
    }
    __syncthreads();

    const int NT = K >> 6;               // 16
    for (int t = 0; t < NT; ++t) {
        const int cur = t & 1;
        if (t + 1 < NT) {                // stage next tile into buf^1
            const int k0 = (t + 1) << 6;
#pragma unroll
            for (int q = 0; q < 4; q++) {
                const int r0 = w * 32 + q * 8;
                stage8(&A[(size_t)(tileM + r0) * K + k0], K,
                       &As[cur ^ 1][r0 * 64], lane);
            }
#pragma unroll
            for (int q = 0; q < 3; q++) {
                const int r0 = w * 24 + q * 8;
                stage8(&Wqkv[(size_t)(tileN + r0) * K + k0], K,
                       &Bs[cur ^ 1][r0 * 64], lane);
            }
        }

#pragma unroll
        for (int p = 0; p < 4; ++p) {
            const int mh = p & 1;        // m-half: frags 0-3 / 4-7
            const int ss = p >> 1;       // k-slice within BK=64
            const int phys = ((ss * 4 + quad) ^ par4) << 3;
            bf16x8 af[4], bfr[3];
#pragma unroll
            for (int i = 0; i < 4; i++)
                af[i] = *(bf16x8*)&As[cur][(wm + (mh * 4 + i) * 16 + l15) * 64 + phys];
#pragma unroll
            for (int j = 0; j < 3; j++)
                bfr[j] = *(bf16x8*)&Bs[cur][(wn + j * 16 + l15) * 64 + phys];
            __builtin_amdgcn_s_setprio(1);
#pragma unroll
            for (int i = 0; i < 4; i++)
#pragma unroll
                for (int j = 0; j < 3; j++)
                    acc[mh * 4 + i][j] = __builtin_amdgcn_mfma_f32_16x16x32_bf16(
                        af[i], bfr[j], acc[mh * 4 + i][j], 0, 0, 0);
            __builtin_amdgcn_s_setprio(0);
            if (p < 3) __builtin_amdgcn_s_barrier();
        }
        __syncthreads();                 // drain vmcnt + buffer-swap guard
    }

    // epilogue: region per 16-col fragment (16-aligned -> never straddles)
#pragma unroll
    for (int i = 0; i < 8; i++) {
        const int row = tileM + wm + i * 16 + quad * 4;
#pragma unroll
        for (int j = 0; j < 3; j++) {
            const int ncol = tileN + wn + j * 16 + l15;
            const int region = ncol >> 10;   // 0=Q, 1=K, 2=V
            if (region == 2) {
                const int cl = ncol - 2048;
                const int h = cl >> 6, d = cl & 63;
                const int bb = row >> 11, tloc = row & (TT - 1);
                bf16x4 pk;
#pragma unroll
                for (int r = 0; r < 4; r++) pk[r] = (bf16_t)acc[i][j][r];
                *(bf16x4*)&Vto[(((size_t)bb * HH + h) * HD + d) * TT + tloc] = pk;
            } else {
                bf16_t* dst = (region == 0) ? Qo : Ko;
                const int cl = ncol & 1023;
#pragma unroll
                for (int r = 0; r < 4; r++)
                    dst[(size_t)(row + r) * DDIM + cl] = (bf16_t)acc[i][j][r];
            }
        }
    }
}

// ---------------------------------------------------------------------------
// Output-projection GEMM, 64x128 tile, BK=64 XOR-staged, fp32 out.
// Grid (8, M/64) = 1024 blocks at M=8192 (4/CU).
// ---------------------------------------------------------------------------
__global__ __launch_bounds__(256) void gemm_out(
    const bf16_t* __restrict__ A, const bf16_t* __restrict__ Bm,
    float* __restrict__ C, int M, int N, int K)
{
    __shared__ alignas(16) bf16_t As[64 * 64];
    __shared__ alignas(16) bf16_t Bs[128 * 64];

    const int tid  = threadIdx.x;
    const int lane = tid & 63;
    const int w    = tid >> 6;
    const int quad = lane >> 4;
    const int l15  = lane & 15;
    const int wm   = (w >> 1) * 32;
    const int wn   = (w & 1) * 64;
    const int tileN = blockIdx.x * 128;
    const int tileM = blockIdx.y * 64;

    const f32x4 vzero = {0.f, 0.f, 0.f, 0.f};
    f32x4 acc[2][4];
#pragma unroll
    for (int i = 0; i < 2; i++)
#pragma unroll
        for (int j = 0; j < 4; j++) acc[i][j] = vzero;

    const int par4 = (l15 & 1) << 2;

    for (int k0 = 0; k0 < K; k0 += 64) {
        __syncthreads();
#pragma unroll
        for (int q = 0; q < 2; q++) {
            const int r0 = w * 16 + q * 8;
            stage8(&A[(size_t)(tileM + r0) * K + k0], K, &As[r0 * 64], lane);
        }
#pragma unroll
        for (int q = 0; q < 4; q++) {
            const int r0 = w * 32 + q * 8;
            stage8(&Bm[(size_t)(tileN + r0) * K + k0], K, &Bs[r0 * 64], lane);
        }
        __syncthreads();

#pragma unroll
        for (int ss = 0; ss < 2; ss++) {
            const int phys = ((ss * 4 + quad) ^ par4) << 3;
            bf16x8 af[2], bf[4];
#pragma unroll
            for (int i = 0; i < 2; i++)
                af[i] = *(bf16x8*)&As[(wm + i * 16 + l15) * 64 + phys];
#pragma unroll
            for (int j = 0; j < 4; j++)
                bf[j] = *(bf16x8*)&Bs[(wn + j * 16 + l15) * 64 + phys];
#pragma unroll
            for (int i = 0; i < 2; i++)
#pragma unroll
                for (int j = 0; j < 4; j++)
                    acc[i][j] = __builtin_amdgcn_mfma_f32_16x16x32_bf16(
                        af[i], bf[j], acc[i][j], 0, 0, 0);
        }
    }

#pragma unroll
    for (int i = 0; i < 2; i++) {
#pragma unroll
        for (int r = 0; r < 4; r++) {
            const int row = tileM + wm + i * 16 + quad * 4 + r;
#pragma unroll
            for (int j = 0; j < 4; j++)
                C[(size_t)row * N + tileN + wn + j * 16 + l15] = acc[i][j][r];
        }
    }
}

// ---------------------------------------------------------------------------
// Flash causal attention v7: T14 async-stage prefetch + T5 setprio +
// folded exp2 (see round-1 notes; 77.5us, MfmaUtil 20.6). Unchanged this
// round for attribution.
// ---------------------------------------------------------------------------
__global__ __launch_bounds__(256, 2) void attn_causal(
    const bf16_t* __restrict__ Q, const bf16_t* __restrict__ Kg,
    const bf16_t* __restrict__ Vt_g, bf16_t* __restrict__ Y)
{
    __shared__ alignas(16) bf16_t Ks[64 * 72];    // [key][d]
    __shared__ alignas(16) bf16_t Vt[64 * 72];    // [d][key]
    __shared__ alignas(16) bf16_t Ps[4][32 * 72]; // per-wave P, chunk-swizzled

    const int tid  = threadIdx.x;
    const int lane = tid & 63;
    const int w    = tid >> 6;
    const int quad = lane >> 4;
    const int l15  = lane & 15;
    const int bh   = blockIdx.x;
    const int sp   = blockIdx.y;         // 0..7
    const int b = bh >> 4, h = bh & 15;

    const int stg_row = tid >> 3;        // 0..31
    const int stg_c8  = (tid & 7) * 8;

    const f32x4 vzero = {0.f, 0.f, 0.f, 0.f};
    bf16x8 ones;
#pragma unroll
    for (int j = 0; j < 8; j++) ones[j] = (l15 == 0) ? (bf16_t)1.0f : (bf16_t)0.0f;

    // kt-invariant per-thread staging addresses
    const bf16_t* kg0 = &Kg[(size_t)(b * TT + stg_row) * DDIM + h * 64 + stg_c8];
    const bf16_t* vg0 = &Vt_g[((size_t)bh * HD + stg_row) * TT + stg_c8];
    bf16_t* ksd = &Ks[stg_row * 72 + stg_c8];
    bf16_t* vtd = &Vt[stg_row * 72 + stg_c8];

    const float SC_LOG2E = 0.125f * 1.44269504f;   // fold scale into exp2

#pragma unroll 1
    for (int half = 0; half < 2; half++) {
        const int strip = half ? (15 - sp) : sp;   // 0..15, 128 rows
        const int qbase = strip * 128;

        bf16x8 qf[2][2];
#pragma unroll
        for (int mi = 0; mi < 2; mi++) {
            const size_t rq =
                (size_t)(b * TT + qbase + w * 32 + mi * 16 + l15) * DDIM + h * 64;
            qf[mi][0] = *(const bf16x8*)&Q[rq + quad * 8];
            qf[mi][1] = *(const bf16x8*)&Q[rq + 32 + quad * 8];
        }

        f32x4 o[2][4], o4[2];
#pragma unroll
        for (int mi = 0; mi < 2; mi++) {
#pragma unroll
            for (int c = 0; c < 4; c++) o[mi][c] = vzero;
            o4[mi] = vzero;
        }

        const int nkt = 2 * strip + 2;

        // T14 prologue: prefetch key-tile 0 into registers
        bf16x8 kreg[2], vreg[2];
#pragma unroll
        for (int p = 0; p < 2; p++) {
            kreg[p] = *(const bf16x8*)&kg0[(size_t)(p * 32) * DDIM];
            vreg[p] = *(const bf16x8*)&vg0[(size_t)(p * 32) * TT];
        }

#pragma unroll 1
        for (int kt = 0; kt < nkt; kt++) {
            const int kbase = kt * 64;
            __syncthreads();                    // readers of prev tile done
            // retire prefetched regs into LDS (vmcnt wait lands here)
#pragma unroll
            for (int p = 0; p < 2; p++) {
                *(bf16x8*)&ksd[p * 32 * 72] = kreg[p];
                *(bf16x8*)&vtd[p * 32 * 72] = vreg[p];
            }
            // issue next tile's global loads; latency hides under compute
            if (kt + 1 < nkt) {
                const int nb = (kt + 1) * 64;
#pragma unroll
                for (int p = 0; p < 2; p++) {
                    kreg[p] = *(const bf16x8*)&kg0[(size_t)(nb + p * 32) * DDIM];
                    vreg[p] = *(const bf16x8*)&vg0[(size_t)(p * 32) * TT + nb];
                }
            }
            __syncthreads();

            // S = Q·K^T : shared kf reads across both m-fragments
            f32x4 s[2][4];
            __builtin_amdgcn_s_setprio(1);
#pragma unroll
            for (int c = 0; c < 4; c++) {
                bf16x8 kf0 = *(bf16x8*)&Ks[(c * 16 + l15) * 72 + quad * 8];
                bf16x8 kf1 = *(bf16x8*)&Ks[(c * 16 + l15) * 72 + 32 + quad * 8];
#pragma unroll
                for (int mi = 0; mi < 2; mi++) {
                    f32x4 t = __builtin_amdgcn_mfma_f32_16x16x32_bf16(
                        qf[mi][0], kf0, vzero, 0, 0, 0);
                    s[mi][c] = __builtin_amdgcn_mfma_f32_16x16x32_bf16(
                        qf[mi][1], kf1, t, 0, 0, 0);
                }
            }
            __builtin_amdgcn_s_setprio(0);

            // p = exp2(s*scale*log2e), mask where tile straddles the diagonal
#pragma unroll
            for (int mi = 0; mi < 2; mi++) {
                const int qlow = qbase + w * 32 + mi * 16;
                const bool need = (kbase + 63 > qlow);   // wave-uniform
#pragma unroll
                for (int r = 0; r < 4; r++) {
                    const int qrow = qlow + quad * 4 + r;
                    const int prow = mi * 16 + quad * 4 + r;
#pragma unroll
                    for (int c = 0; c < 4; c++) {
                        float sv = s[mi][c][r] * SC_LOG2E;
                        if (need && (kbase + c * 16 + l15 > qrow)) sv = -1e30f;
                        const int pchunk = (c * 2 + (l15 >> 3)) ^ (prow >> 2);
                        Ps[w][prow * 72 + (pchunk << 3) + (l15 & 7)] =
                            (bf16_t)__builtin_amdgcn_exp2f(sv);
                    }
                }
            }
            // Ps wave-private: same-wave RAW via lgkmcnt, no barrier.

            // O += P·V ; o4 += P·ones
            __builtin_amdgcn_s_setprio(1);
#pragma unroll
            for (int ss = 0; ss < 2; ss++) {
                bf16x8 pf[2];
#pragma unroll
                for (int mi = 0; mi < 2; mi++) {
                    const int m = mi * 16 + l15;
                    pf[mi] = *(bf16x8*)&Ps[w][m * 72 +
                                              ((((ss * 4 + quad) ^ (m >> 2)) & 7) << 3)];
                }
#pragma unroll
                for (int c = 0; c < 4; c++) {
                    bf16x8 vf = *(bf16x8*)&Vt[(c * 16 + l15) * 72 + ss * 32 + quad * 8];
#pragma unroll
                    for (int mi = 0; mi < 2; mi++)
                        o[mi][c] = __builtin_amdgcn_mfma_f32_16x16x32_bf16(
                            pf[mi], vf, o[mi][c], 0, 0, 0);
                }
#pragma unroll
                for (int mi = 0; mi < 2; mi++)
                    o4[mi] = __builtin_amdgcn_mfma_f32_16x16x32_bf16(
                        pf[mi], ones, o4[mi], 0, 0, 0);
            }
            __builtin_amdgcn_s_setprio(0);
        }

        // epilogue: row-sum lives in lane l15==0 of each quad group
#pragma unroll
        for (int mi = 0; mi < 2; mi++) {
#pragma unroll
            for (int r = 0; r < 4; r++) {
                const float lsum = __shfl(o4[mi][r], lane & 48, 64);
                const float inv = 1.0f / lsum;
                const int q = qbase + w * 32 + mi * 16 + quad * 4 + r;
#pragma unroll
                for (int c = 0; c < 4; c++)
                    Y[(size_t)(b * TT + q) * DDIM + h * 64 + c * 16 + l15] =
                        (bf16_t)(o[mi][c][r] * inv);
            }
        }
    }
}

extern "C" void kernel_launch(void* const* d_in, const int* in_sizes, int n_in,
                              void* d_out, int out_size, void* d_ws, size_t ws_size,
                              hipStream_t stream) {
    (void)in_sizes; (void)n_in; (void)out_size;
    const float* x  = (const float*)d_in[0];
    float* out = (float*)d_out;

    const int M = BB * TT;                     // 8192
    const size_t REGION = (size_t)M * DDIM;    // 8M elems
    const size_t WREG   = (size_t)DDIM * DDIM; // 1M elems
    const size_t BATCH  = (size_t)TT * DDIM;   // 2M elems
    bf16_t* ws = (bf16_t*)d_ws;

    if (ws_size >= (72ull << 20)) {
        // Full path: xb(8M) wpk(4M) Qb(8M) Kb(8M) Vtb(8M) = 36M bf16 = 72 MiB.
        bf16_t* xb  = ws;
        bf16_t* wpk = ws + REGION;
        bf16_t* Qb  = wpk + 4 * WREG;
        bf16_t* Kb  = Qb + REGION;
        bf16_t* Vtb = Kb + REGION;

        cvt_f32_bf16<<<1024, 256, 0, stream>>>(x, xb, REGION / 8);
        cvt_wpack<<<512, 256, 0, stream>>>(
            (const float*)d_in[1], (const float*)d_in[2],
            (const float*)d_in[3], (const float*)d_in[4], wpk);

        gemm_qkv<<<dim3(16, M / 256), 512, 0, stream>>>(
            xb, wpk, Qb, Kb, Vtb, M, DDIM);
        attn_causal<<<dim3(BB * HH, 8), 256, 0, stream>>>(Qb, Kb, Vtb, Qb);
        gemm_out<<<dim3(8, M / 64), 256, 0, stream>>>(
            Qb, wpk + 3 * WREG, out, M, DDIM, DDIM);
    } else {
        // Per-batch path: wpk(4M) + xb(2M) + Qb,Kb,Vtb(3x2M) = 12M = 24 MiB.
        bf16_t* wpk = ws;
        bf16_t* xbb = ws + 4 * WREG;
        bf16_t* Qb  = xbb + BATCH;
        bf16_t* Kb  = Qb + BATCH;
        bf16_t* Vtb = Kb + BATCH;

        cvt_wpack<<<512, 256, 0, stream>>>(
            (const float*)d_in[1], (const float*)d_in[2],
            (const float*)d_in[3], (const float*)d_in[4], wpk);

        for (int b = 0; b < BB; b++) {
            const float* x_b = x + (size_t)b * BATCH;
            float* out_b = out + (size_t)b * BATCH;
            cvt_f32_bf16<<<512, 256, 0, stream>>>(x_b, xbb, BATCH / 8);
            gemm_qkv<<<dim3(16, TT / 256), 512, 0, stream>>>(
                xbb, wpk, Qb, Kb, Vtb, TT, DDIM);
            attn_causal<<<dim3(HH, 8), 256, 0, stream>>>(Qb, Kb, Vtb, Qb);
            gemm_out<<<dim3(8, TT / 64), 256, 0, stream>>>(
                Qb, wpk + 3 * WREG, out_b, TT, DDIM, DDIM);
        }
    }
}

// Round 3
// 257.458 us; speedup vs baseline: 1.1479x; 1.1479x over previous
//
#include <hip/hip_runtime.h>
#include <hip/hip_bf16.h>

#define BB 4
#define TT 2048
#define DDIM 1024
#define HH 16
#define HD 64

typedef __bf16 bf16_t;
typedef __bf16 bf16x4 __attribute__((ext_vector_type(4)));
typedef __bf16 bf16x8 __attribute__((ext_vector_type(8)));
typedef float f32x4 __attribute__((ext_vector_type(4)));

#define GLOAD_LDS(gp, lp) \
    __builtin_amdgcn_global_load_lds( \
        (const __attribute__((address_space(1))) void*)(gp), \
        (__attribute__((address_space(3))) void*)(lp), 16, 0, 0)

// ---------------------------------------------------------------------------
// fp32 -> bf16 conversion, 8 elems/thread, grid-stride. n8 = n/8.
// ---------------------------------------------------------------------------
__global__ __launch_bounds__(256) void cvt_f32_bf16(
    const float* __restrict__ src, bf16_t* __restrict__ dst, size_t n8)
{
    size_t i = (size_t)blockIdx.x * blockDim.x + threadIdx.x;
    const size_t stride = (size_t)gridDim.x * blockDim.x;
    for (; i < n8; i += stride) {
        const f32x4 a = ((const f32x4*)src)[2 * i];
        const f32x4 b = ((const f32x4*)src)[2 * i + 1];
        bf16x8 v;
#pragma unroll
        for (int j = 0; j < 4; j++) { v[j] = (bf16_t)a[j]; v[4 + j] = (bf16_t)b[j]; }
        ((bf16x8*)dst)[i] = v;
    }
}

// Pack 4 fp32 weight matrices into one bf16 buffer [wq|wk|wv|wo].
__global__ __launch_bounds__(256) void cvt_wpack(
    const float* __restrict__ s0, const float* __restrict__ s1,
    const float* __restrict__ s2, const float* __restrict__ s3,
    bf16_t* __restrict__ dst)
{
    const size_t n8 = (size_t)4 * DDIM * DDIM / 8;
    size_t i = (size_t)blockIdx.x * blockDim.x + threadIdx.x;
    const size_t stride = (size_t)gridDim.x * blockDim.x;
    for (; i < n8; i += stride) {
        const int sel = (int)(i >> 17);
        const float* s = sel == 0 ? s0 : sel == 1 ? s1 : sel == 2 ? s2 : s3;
        const size_t off8 = i & ((1u << 17) - 1);
        const f32x4 a = ((const f32x4*)s)[2 * off8];
        const f32x4 b = ((const f32x4*)s)[2 * off8 + 1];
        bf16x8 v;
#pragma unroll
        for (int j = 0; j < 4; j++) { v[j] = (bf16_t)a[j]; v[4 + j] = (bf16_t)b[j]; }
        ((bf16x8*)dst)[i] = v;
    }
}

// ---------------------------------------------------------------------------
// BK=64 XOR-row staging (global_load_lds cannot scatter per lane, so the
// GLOBAL source column is permuted instead): LDS[row][c] = G[row][c ^
// ((row&1)*4)] at 8-elem chunk granularity. Fragment reads un-XOR ->
// bank-balanced (8 slots x 8 lanes) despite the 128B row stride.
// Stages 8 rows per instruction: lane -> row lane>>3, chunk lane&7.
// ---------------------------------------------------------------------------
__device__ __forceinline__ void stage8(const bf16_t* __restrict__ g, int ld,
                                       bf16_t* __restrict__ ldsbase, int lane)
{
    const int rr = lane >> 3;
    const int cc = (lane & 7) ^ ((rr & 1) << 2);
    GLOAD_LDS(&g[(size_t)rr * ld + cc * 8], ldsbase);
}

// ---------------------------------------------------------------------------
// Fused QKV GEMM (round-1 structure, harness-verified at 77.7us, + T1 XCD
// swizzle): A[M,1024] · Wqkv[3072,1024]^T. 128x128 tile, BK=64, 16 k-iters,
// 32 MFMA/stage, 256 thr, 2 blocks/CU. Round-2's coarse phase-split
// regressed (107us: drain-0 vmcnt + 1 block/CU lockstep = m196's known-bad
// variant) -- reverted. T1: consecutive original block ids share the A
// row-panel; remapping hw-id%8 -> contiguous id chunks makes each XCD's L2
// hold one A panel slice (bijective: nwg=1536/384, both %8==0).
// Epilogue per block-uniform region: Q natural / K natural / V [B,H,HD,T].
// ---------------------------------------------------------------------------
__global__ __launch_bounds__(256) void gemm_qkv(
    const bf16_t* __restrict__ A, const bf16_t* __restrict__ Wqkv,
    bf16_t* __restrict__ Qo, bf16_t* __restrict__ Ko, bf16_t* __restrict__ Vto,
    int M, int K)
{
    __shared__ alignas(16) bf16_t As[128 * 64];
    __shared__ alignas(16) bf16_t Bs[128 * 64];

    const int tid  = threadIdx.x;
    const int lane = tid & 63;
    const int w    = tid >> 6;
    const int quad = lane >> 4;
    const int l15  = lane & 15;
    const int wm   = (w >> 1) * 64;
    const int wn   = (w & 1) * 64;

    // T1 XCD swizzle: hw linear id -> contiguous chunk per XCD
    const int nwg = gridDim.x * gridDim.y;
    const int cpx = nwg >> 3;
    int id = blockIdx.y * gridDim.x + blockIdx.x;
    id = (id & 7) * cpx + (id >> 3);
    const int tileN = (id % 24) * 128;     // gridDim.x == 24 in both paths
    const int tileM = (id / 24) * 128;

    const f32x4 vzero = {0.f, 0.f, 0.f, 0.f};
    f32x4 acc[4][4];
#pragma unroll
    for (int i = 0; i < 4; i++)
#pragma unroll
        for (int j = 0; j < 4; j++) acc[i][j] = vzero;

    const int par4 = (l15 & 1) << 2;     // read-side un-XOR

    for (int k0 = 0; k0 < K; k0 += 64) {
        __syncthreads();
#pragma unroll
        for (int q = 0; q < 4; q++) {
            const int r0 = w * 32 + q * 8;
            stage8(&A[(size_t)(tileM + r0) * K + k0], K, &As[r0 * 64], lane);
            stage8(&Wqkv[(size_t)(tileN + r0) * K + k0], K, &Bs[r0 * 64], lane);
        }
        __syncthreads();

#pragma unroll
        for (int ss = 0; ss < 2; ss++) {
            const int phys = ((ss * 4 + quad) ^ par4) << 3;
            bf16x8 af[4], bf[4];
#pragma unroll
            for (int i = 0; i < 4; i++)
                af[i] = *(bf16x8*)&As[(wm + i * 16 + l15) * 64 + phys];
#pragma unroll
            for (int j = 0; j < 4; j++)
                bf[j] = *(bf16x8*)&Bs[(wn + j * 16 + l15) * 64 + phys];
#pragma unroll
            for (int i = 0; i < 4; i++)
#pragma unroll
                for (int j = 0; j < 4; j++)
                    acc[i][j] = __builtin_amdgcn_mfma_f32_16x16x32_bf16(
                        af[i], bf[j], acc[i][j], 0, 0, 0);
        }
    }

    const int region = tileN >> 10;    // 0=Q, 1=K, 2=V (block-uniform)
#pragma unroll
    for (int i = 0; i < 4; i++) {
        const int row = tileM + wm + i * 16 + quad * 4;
#pragma unroll
        for (int j = 0; j < 4; j++) {
            const int ncol = tileN + wn + j * 16 + l15;
            if (region == 2) {
                const int cl = ncol - 2048;
                const int h = cl >> 6, d = cl & 63;
                const int bb = row >> 11, tloc = row & (TT - 1);
                bf16x4 pk;
#pragma unroll
                for (int r = 0; r < 4; r++) pk[r] = (bf16_t)acc[i][j][r];
                *(bf16x4*)&Vto[(((size_t)bb * HH + h) * HD + d) * TT + tloc] = pk;
            } else {
                bf16_t* dst = (region == 0) ? Qo : Ko;
                const int cl = ncol & 1023;
#pragma unroll
                for (int r = 0; r < 4; r++)
                    dst[(size_t)(row + r) * DDIM + cl] = (bf16_t)acc[i][j][r];
            }
        }
    }
}

// ---------------------------------------------------------------------------
// Output-projection GEMM, 64x128 tile, BK=64 XOR-staged, fp32 out.
// Grid (8, M/64) = 1024 blocks at M=8192 (4/CU).
// ---------------------------------------------------------------------------
__global__ __launch_bounds__(256) void gemm_out(
    const bf16_t* __restrict__ A, const bf16_t* __restrict__ Bm,
    float* __restrict__ C, int M, int N, int K)
{
    __shared__ alignas(16) bf16_t As[64 * 64];
    __shared__ alignas(16) bf16_t Bs[128 * 64];

    const int tid  = threadIdx.x;
    const int lane = tid & 63;
    const int w    = tid >> 6;
    const int quad = lane >> 4;
    const int l15  = lane & 15;
    const int wm   = (w >> 1) * 32;
    const int wn   = (w & 1) * 64;
    const int tileN = blockIdx.x * 128;
    const int tileM = blockIdx.y * 64;

    const f32x4 vzero = {0.f, 0.f, 0.f, 0.f};
    f32x4 acc[2][4];
#pragma unroll
    for (int i = 0; i < 2; i++)
#pragma unroll
        for (int j = 0; j < 4; j++) acc[i][j] = vzero;

    const int par4 = (l15 & 1) << 2;

    for (int k0 = 0; k0 < K; k0 += 64) {
        __syncthreads();
#pragma unroll
        for (int q = 0; q < 2; q++) {
            const int r0 = w * 16 + q * 8;
            stage8(&A[(size_t)(tileM + r0) * K + k0], K, &As[r0 * 64], lane);
        }
#pragma unroll
        for (int q = 0; q < 4; q++) {
            const int r0 = w * 32 + q * 8;
            stage8(&Bm[(size_t)(tileN + r0) * K + k0], K, &Bs[r0 * 64], lane);
        }
        __syncthreads();

#pragma unroll
        for (int ss = 0; ss < 2; ss++) {
            const int phys = ((ss * 4 + quad) ^ par4) << 3;
            bf16x8 af[2], bf[4];
#pragma unroll
            for (int i = 0; i < 2; i++)
                af[i] = *(bf16x8*)&As[(wm + i * 16 + l15) * 64 + phys];
#pragma unroll
            for (int j = 0; j < 4; j++)
                bf[j] = *(bf16x8*)&Bs[(wn + j * 16 + l15) * 64 + phys];
#pragma unroll
            for (int i = 0; i < 2; i++)
#pragma unroll
                for (int j = 0; j < 4; j++)
                    acc[i][j] = __builtin_amdgcn_mfma_f32_16x16x32_bf16(
                        af[i], bf[j], acc[i][j], 0, 0, 0);
        }
    }

#pragma unroll
    for (int i = 0; i < 2; i++) {
#pragma unroll
        for (int r = 0; r < 4; r++) {
            const int row = tileM + wm + i * 16 + quad * 4 + r;
#pragma unroll
            for (int j = 0; j < 4; j++)
                C[(size_t)row * N + tileN + wn + j * 16 + l15] = acc[i][j][r];
        }
    }
}

// ---------------------------------------------------------------------------
// Flash causal attention v8: v7 (T14 reg prefetch + setprio + exp2) + LDS
// double-buffer for Ks/Vt. One __syncthreads per key-tile instead of two:
// buf[kt&1] was last read at kt-2, and every wave passes kt-1's barrier
// only after finishing its kt-2 compute, so the top-of-tile ds_write is
// race-free without a pre-write barrier. nkt = 2*strip+2 is always EVEN,
// so the cross-half buffer parity stays safe (half-1's kt=0 writes buf0,
// last read at half-0's kt=nkt0-2, guarded by kt=nkt0-1's barrier).
// LDS 54 KiB -> still 2 blocks/CU.
// Grid (nbh, 8): block handles strips sp and 15-sp (34 key-tiles, uniform);
// linear id mod 8 keeps each (b,h)'s K/V slab XCD-local.
// No-max softmax; Ps chunk-swizzled; row-sums via ones-MFMA; Y aliases Q.
// ---------------------------------------------------------------------------
__global__ __launch_bounds__(256, 2) void attn_causal(
    const bf16_t* __restrict__ Q, const bf16_t* __restrict__ Kg,
    const bf16_t* __restrict__ Vt_g, bf16_t* __restrict__ Y)
{
    __shared__ alignas(16) bf16_t Ks[2 * 64 * 72];  // [buf][key][d]
    __shared__ alignas(16) bf16_t Vt[2 * 64 * 72];  // [buf][d][key]
    __shared__ alignas(16) bf16_t Ps[4][32 * 72];   // per-wave P, chunk-swizzled

    const int tid  = threadIdx.x;
    const int lane = tid & 63;
    const int w    = tid >> 6;
    const int quad = lane >> 4;
    const int l15  = lane & 15;
    const int bh   = blockIdx.x;
    const int sp   = blockIdx.y;         // 0..7
    const int b = bh >> 4, h = bh & 15;

    const int stg_row = tid >> 3;        // 0..31
    const int stg_c8  = (tid & 7) * 8;
    const int stg_off = stg_row * 72 + stg_c8;

    const f32x4 vzero = {0.f, 0.f, 0.f, 0.f};
    bf16x8 ones;
#pragma unroll
    for (int j = 0; j < 8; j++) ones[j] = (l15 == 0) ? (bf16_t)1.0f : (bf16_t)0.0f;

    // kt-invariant per-thread staging addresses
    const bf16_t* kg0 = &Kg[(size_t)(b * TT + stg_row) * DDIM + h * 64 + stg_c8];
    const bf16_t* vg0 = &Vt_g[((size_t)bh * HD + stg_row) * TT + stg_c8];

    const float SC_LOG2E = 0.125f * 1.44269504f;   // fold scale into exp2

#pragma unroll 1
    for (int half = 0; half < 2; half++) {
        const int strip = half ? (15 - sp) : sp;   // 0..15, 128 rows
        const int qbase = strip * 128;

        bf16x8 qf[2][2];
#pragma unroll
        for (int mi = 0; mi < 2; mi++) {
            const size_t rq =
                (size_t)(b * TT + qbase + w * 32 + mi * 16 + l15) * DDIM + h * 64;
            qf[mi][0] = *(const bf16x8*)&Q[rq + quad * 8];
            qf[mi][1] = *(const bf16x8*)&Q[rq + 32 + quad * 8];
        }

        f32x4 o[2][4], o4[2];
#pragma unroll
        for (int mi = 0; mi < 2; mi++) {
#pragma unroll
            for (int c = 0; c < 4; c++) o[mi][c] = vzero;
            o4[mi] = vzero;
        }

        const int nkt = 2 * strip + 2;   // always even

        // T14 prologue: prefetch key-tile 0 into registers
        bf16x8 kreg[2], vreg[2];
#pragma unroll
        for (int p = 0; p < 2; p++) {
            kreg[p] = *(const bf16x8*)&kg0[(size_t)(p * 32) * DDIM];
            vreg[p] = *(const bf16x8*)&vg0[(size_t)(p * 32) * TT];
        }

#pragma unroll 1
        for (int kt = 0; kt < nkt; kt++) {
            const int kbase = kt * 64;
            const int coff = (kt & 1) * (64 * 72);
            // retire prefetched regs into buf[kt&1] (race-free: see header)
#pragma unroll
            for (int p = 0; p < 2; p++) {
                *(bf16x8*)&Ks[coff + stg_off + p * 32 * 72] = kreg[p];
                *(bf16x8*)&Vt[coff + stg_off + p * 32 * 72] = vreg[p];
            }
            // issue next tile's global loads; latency hides under compute
            if (kt + 1 < nkt) {
                const int nb = (kt + 1) * 64;
#pragma unroll
                for (int p = 0; p < 2; p++) {
                    kreg[p] = *(const bf16x8*)&kg0[(size_t)(nb + p * 32) * DDIM];
                    vreg[p] = *(const bf16x8*)&vg0[(size_t)(p * 32) * TT + nb];
                }
            }
            __syncthreads();             // single barrier per key-tile

            // S = Q·K^T : shared kf reads across both m-fragments
            f32x4 s[2][4];
            __builtin_amdgcn_s_setprio(1);
#pragma unroll
            for (int c = 0; c < 4; c++) {
                bf16x8 kf0 = *(bf16x8*)&Ks[coff + (c * 16 + l15) * 72 + quad * 8];
                bf16x8 kf1 = *(bf16x8*)&Ks[coff + (c * 16 + l15) * 72 + 32 + quad * 8];
#pragma unroll
                for (int mi = 0; mi < 2; mi++) {
                    f32x4 t = __builtin_amdgcn_mfma_f32_16x16x32_bf16(
                        qf[mi][0], kf0, vzero, 0, 0, 0);
                    s[mi][c] = __builtin_amdgcn_mfma_f32_16x16x32_bf16(
                        qf[mi][1], kf1, t, 0, 0, 0);
                }
            }
            __builtin_amdgcn_s_setprio(0);

            // p = exp2(s*scale*log2e), mask where tile straddles the diagonal
#pragma unroll
            for (int mi = 0; mi < 2; mi++) {
                const int qlow = qbase + w * 32 + mi * 16;
                const bool need = (kbase + 63 > qlow);   // wave-uniform
#pragma unroll
                for (int r = 0; r < 4; r++) {
                    const int qrow = qlow + quad * 4 + r;
                    const int prow = mi * 16 + quad * 4 + r;
#pragma unroll
                    for (int c = 0; c < 4; c++) {
                        float sv = s[mi][c][r] * SC_LOG2E;
                        if (need && (kbase + c * 16 + l15 > qrow)) sv = -1e30f;
                        const int pchunk = (c * 2 + (l15 >> 3)) ^ (prow >> 2);
                        Ps[w][prow * 72 + (pchunk << 3) + (l15 & 7)] =
                            (bf16_t)__builtin_amdgcn_exp2f(sv);
                    }
                }
            }
            // Ps wave-private: same-wave RAW via lgkmcnt, no barrier.

            // O += P·V ; o4 += P·ones
            __builtin_amdgcn_s_setprio(1);
#pragma unroll
            for (int ss = 0; ss < 2; ss++) {
                bf16x8 pf[2];
#pragma unroll
                for (int mi = 0; mi < 2; mi++) {
                    const int m = mi * 16 + l15;
                    pf[mi] = *(bf16x8*)&Ps[w][m * 72 +
                                              ((((ss * 4 + quad) ^ (m >> 2)) & 7) << 3)];
                }
#pragma unroll
                for (int c = 0; c < 4; c++) {
                    bf16x8 vf = *(bf16x8*)&Vt[coff + (c * 16 + l15) * 72 + ss * 32 + quad * 8];
#pragma unroll
                    for (int mi = 0; mi < 2; mi++)
                        o[mi][c] = __builtin_amdgcn_mfma_f32_16x16x32_bf16(
                            pf[mi], vf, o[mi][c], 0, 0, 0);
                }
#pragma unroll
                for (int mi = 0; mi < 2; mi++)
                    o4[mi] = __builtin_amdgcn_mfma_f32_16x16x32_bf16(
                        pf[mi], ones, o4[mi], 0, 0, 0);
            }
            __builtin_amdgcn_s_setprio(0);
        }

        // epilogue: row-sum lives in lane l15==0 of each quad group
#pragma unroll
        for (int mi = 0; mi < 2; mi++) {
#pragma unroll
            for (int r = 0; r < 4; r++) {
                const float lsum = __shfl(o4[mi][r], lane & 48, 64);
                const float inv = 1.0f / lsum;
                const int q = qbase + w * 32 + mi * 16 + quad * 4 + r;
#pragma unroll
                for (int c = 0; c < 4; c++)
                    Y[(size_t)(b * TT + q) * DDIM + h * 64 + c * 16 + l15] =
                        (bf16_t)(o[mi][c][r] * inv);
            }
        }
    }
}

extern "C" void kernel_launch(void* const* d_in, const int* in_sizes, int n_in,
                              void* d_out, int out_size, void* d_ws, size_t ws_size,
                              hipStream_t stream) {
    (void)in_sizes; (void)n_in; (void)out_size;
    const float* x  = (const float*)d_in[0];
    float* out = (float*)d_out;

    const int M = BB * TT;                     // 8192
    const size_t REGION = (size_t)M * DDIM;    // 8M elems
    const size_t WREG   = (size_t)DDIM * DDIM; // 1M elems
    const size_t BATCH  = (size_t)TT * DDIM;   // 2M elems
    bf16_t* ws = (bf16_t*)d_ws;

    if (ws_size >= (72ull << 20)) {
        // Full path: xb(8M) wpk(4M) Qb(8M) Kb(8M) Vtb(8M) = 36M bf16 = 72 MiB.
        bf16_t* xb  = ws;
        bf16_t* wpk = ws + REGION;
        bf16_t* Qb  = wpk + 4 * WREG;
        bf16_t* Kb  = Qb + REGION;
        bf16_t* Vtb = Kb + REGION;

        cvt_f32_bf16<<<1024, 256, 0, stream>>>(x, xb, REGION / 8);
        cvt_wpack<<<512, 256, 0, stream>>>(
            (const float*)d_in[1], (const float*)d_in[2],
            (const float*)d_in[3], (const float*)d_in[4], wpk);

        gemm_qkv<<<dim3(24, M / 128), 256, 0, stream>>>(
            xb, wpk, Qb, Kb, Vtb, M, DDIM);
        attn_causal<<<dim3(BB * HH, 8), 256, 0, stream>>>(Qb, Kb, Vtb, Qb);
        gemm_out<<<dim3(8, M / 64), 256, 0, stream>>>(
            Qb, wpk + 3 * WREG, out, M, DDIM, DDIM);
    } else {
        // Per-batch path: wpk(4M) + xb(2M) + Qb,Kb,Vtb(3x2M) = 12M = 24 MiB.
        bf16_t* wpk = ws;
        bf16_t* xbb = ws + 4 * WREG;
        bf16_t* Qb  = xbb + BATCH;
        bf16_t* Kb  = Qb + BATCH;
        bf16_t* Vtb = Kb + BATCH;

        cvt_wpack<<<512, 256, 0, stream>>>(
            (const float*)d_in[1], (const float*)d_in[2],
            (const float*)d_in[3], (const float*)d_in[4], wpk);

        for (int b = 0; b < BB; b++) {
            const float* x_b = x + (size_t)b * BATCH;
            float* out_b = out + (size_t)b * BATCH;
            cvt_f32_bf16<<<512, 256, 0, stream>>>(x_b, xbb, BATCH / 8);
            gemm_qkv<<<dim3(24, TT / 128), 256, 0, stream>>>(
                xbb, wpk, Qb, Kb, Vtb, TT, DDIM);
            attn_causal<<<dim3(HH, 8), 256, 0, stream>>>(Qb, Kb, Vtb, Qb);
            gemm_out<<<dim3(8, TT / 64), 256, 0, stream>>>(
                Qb, wpk + 3 * WREG, out_b, TT, DDIM, DDIM);
        }
    }
}

// Round 4
// 254.410 us; speedup vs baseline: 1.1616x; 1.0120x over previous
//
#include <hip/hip_runtime.h>
#include <hip/hip_bf16.h>

#define BB 4
#define TT 2048
#define DDIM 1024
#define HH 16
#define HD 64

typedef __bf16 bf16_t;
typedef __bf16 bf16x4 __attribute__((ext_vector_type(4)));
typedef __bf16 bf16x8 __attribute__((ext_vector_type(8)));
typedef float f32x4 __attribute__((ext_vector_type(4)));

#define GLOAD_LDS(gp, lp) \
    __builtin_amdgcn_global_load_lds( \
        (const __attribute__((address_space(1))) void*)(gp), \
        (__attribute__((address_space(3))) void*)(lp), 16, 0, 0)

// ---------------------------------------------------------------------------
// fp32 -> bf16 conversion, 8 elems/thread, grid-stride. n8 = n/8.
// ---------------------------------------------------------------------------
__global__ __launch_bounds__(256) void cvt_f32_bf16(
    const float* __restrict__ src, bf16_t* __restrict__ dst, size_t n8)
{
    size_t i = (size_t)blockIdx.x * blockDim.x + threadIdx.x;
    const size_t stride = (size_t)gridDim.x * blockDim.x;
    for (; i < n8; i += stride) {
        const f32x4 a = ((const f32x4*)src)[2 * i];
        const f32x4 b = ((const f32x4*)src)[2 * i + 1];
        bf16x8 v;
#pragma unroll
        for (int j = 0; j < 4; j++) { v[j] = (bf16_t)a[j]; v[4 + j] = (bf16_t)b[j]; }
        ((bf16x8*)dst)[i] = v;
    }
}

// Pack 4 fp32 weight matrices into one bf16 buffer [wq|wk|wv|wo].
__global__ __launch_bounds__(256) void cvt_wpack(
    const float* __restrict__ s0, const float* __restrict__ s1,
    const float* __restrict__ s2, const float* __restrict__ s3,
    bf16_t* __restrict__ dst)
{
    const size_t n8 = (size_t)4 * DDIM * DDIM / 8;
    size_t i = (size_t)blockIdx.x * blockDim.x + threadIdx.x;
    const size_t stride = (size_t)gridDim.x * blockDim.x;
    for (; i < n8; i += stride) {
        const int sel = (int)(i >> 17);
        const float* s = sel == 0 ? s0 : sel == 1 ? s1 : sel == 2 ? s2 : s3;
        const size_t off8 = i & ((1u << 17) - 1);
        const f32x4 a = ((const f32x4*)s)[2 * off8];
        const f32x4 b = ((const f32x4*)s)[2 * off8 + 1];
        bf16x8 v;
#pragma unroll
        for (int j = 0; j < 4; j++) { v[j] = (bf16_t)a[j]; v[4 + j] = (bf16_t)b[j]; }
        ((bf16x8*)dst)[i] = v;
    }
}

// ---------------------------------------------------------------------------
// BK=64 XOR-row staging (global_load_lds cannot scatter per lane, so the
// GLOBAL source column is permuted instead): LDS[row][c] = G[row][c ^
// ((row&1)*4)] at 8-elem chunk granularity. Fragment reads un-XOR ->
// bank-balanced (8 slots x 8 lanes) despite the 128B row stride.
// Stages 8 rows per instruction: lane -> row lane>>3, chunk lane&7.
// ---------------------------------------------------------------------------
__device__ __forceinline__ void stage8(const bf16_t* __restrict__ g, int ld,
                                       bf16_t* __restrict__ ldsbase, int lane)
{
    const int rr = lane >> 3;
    const int cc = (lane & 7) ^ ((rr & 1) << 2);
    GLOAD_LDS(&g[(size_t)rr * ld + cc * 8], ldsbase);
}

// ---------------------------------------------------------------------------
// Fused QKV GEMM (verified 128x128 structure + T1 swizzle): A[M,1024] ·
// Wqkv[3072,1024]^T. BK=64, 16 k-iters, 32 MFMA/stage, 256 thr, 2 blk/CU.
// NEW: Q-region epilogue pre-scales by 0.125*log2e, so attn's softmax can
// feed exp2 directly (removes 32 VALU muls/lane/tile from attn's hot loop).
// Epilogue per block-uniform region: Q scaled / K natural / V [B,H,HD,T].
// ---------------------------------------------------------------------------
__global__ __launch_bounds__(256) void gemm_qkv(
    const bf16_t* __restrict__ A, const bf16_t* __restrict__ Wqkv,
    bf16_t* __restrict__ Qo, bf16_t* __restrict__ Ko, bf16_t* __restrict__ Vto,
    int M, int K)
{
    __shared__ alignas(16) bf16_t As[128 * 64];
    __shared__ alignas(16) bf16_t Bs[128 * 64];

    const int tid  = threadIdx.x;
    const int lane = tid & 63;
    const int w    = tid >> 6;
    const int quad = lane >> 4;
    const int l15  = lane & 15;
    const int wm   = (w >> 1) * 64;
    const int wn   = (w & 1) * 64;

    // T1 XCD swizzle: hw linear id -> contiguous chunk per XCD
    const int nwg = gridDim.x * gridDim.y;
    const int cpx = nwg >> 3;
    int id = blockIdx.y * gridDim.x + blockIdx.x;
    id = (id & 7) * cpx + (id >> 3);
    const int tileN = (id % 24) * 128;     // gridDim.x == 24 in both paths
    const int tileM = (id / 24) * 128;

    const f32x4 vzero = {0.f, 0.f, 0.f, 0.f};
    f32x4 acc[4][4];
#pragma unroll
    for (int i = 0; i < 4; i++)
#pragma unroll
        for (int j = 0; j < 4; j++) acc[i][j] = vzero;

    const int par4 = (l15 & 1) << 2;     // read-side un-XOR

    for (int k0 = 0; k0 < K; k0 += 64) {
        __syncthreads();
#pragma unroll
        for (int q = 0; q < 4; q++) {
            const int r0 = w * 32 + q * 8;
            stage8(&A[(size_t)(tileM + r0) * K + k0], K, &As[r0 * 64], lane);
            stage8(&Wqkv[(size_t)(tileN + r0) * K + k0], K, &Bs[r0 * 64], lane);
        }
        __syncthreads();

#pragma unroll
        for (int ss = 0; ss < 2; ss++) {
            const int phys = ((ss * 4 + quad) ^ par4) << 3;
            bf16x8 af[4], bf[4];
#pragma unroll
            for (int i = 0; i < 4; i++)
                af[i] = *(bf16x8*)&As[(wm + i * 16 + l15) * 64 + phys];
#pragma unroll
            for (int j = 0; j < 4; j++)
                bf[j] = *(bf16x8*)&Bs[(wn + j * 16 + l15) * 64 + phys];
#pragma unroll
            for (int i = 0; i < 4; i++)
#pragma unroll
                for (int j = 0; j < 4; j++)
                    acc[i][j] = __builtin_amdgcn_mfma_f32_16x16x32_bf16(
                        af[i], bf[j], acc[i][j], 0, 0, 0);
        }
    }

    const int region = tileN >> 10;    // 0=Q, 1=K, 2=V (block-uniform)
    const float osc = (region == 0) ? 0.125f * 1.44269504f : 1.0f;
#pragma unroll
    for (int i = 0; i < 4; i++) {
        const int row = tileM + wm + i * 16 + quad * 4;
#pragma unroll
        for (int j = 0; j < 4; j++) {
            const int ncol = tileN + wn + j * 16 + l15;
            if (region == 2) {
                const int cl = ncol - 2048;
                const int h = cl >> 6, d = cl & 63;
                const int bb = row >> 11, tloc = row & (TT - 1);
                bf16x4 pk;
#pragma unroll
                for (int r = 0; r < 4; r++) pk[r] = (bf16_t)acc[i][j][r];
                *(bf16x4*)&Vto[(((size_t)bb * HH + h) * HD + d) * TT + tloc] = pk;
            } else {
                bf16_t* dst = (region == 0) ? Qo : Ko;
                const int cl = ncol & 1023;
#pragma unroll
                for (int r = 0; r < 4; r++)
                    dst[(size_t)(row + r) * DDIM + cl] = (bf16_t)(acc[i][j][r] * osc);
            }
        }
    }
}

// ---------------------------------------------------------------------------
// Output-projection GEMM v2: upgraded to the verified 128x128 structure
// (was 64x128 at ~450 TF class). BK=64, 16 k-iters, 32 MFMA/stage, 2 blk/CU.
// Grid (8, M/128) = 512 blocks full path (%8==0 -> bijective T1 swizzle).
// fp32 coalesced epilogue.
// ---------------------------------------------------------------------------
__global__ __launch_bounds__(256) void gemm_out(
    const bf16_t* __restrict__ A, const bf16_t* __restrict__ Bm,
    float* __restrict__ C, int M, int N, int K)
{
    __shared__ alignas(16) bf16_t As[128 * 64];
    __shared__ alignas(16) bf16_t Bs[128 * 64];

    const int tid  = threadIdx.x;
    const int lane = tid & 63;
    const int w    = tid >> 6;
    const int quad = lane >> 4;
    const int l15  = lane & 15;
    const int wm   = (w >> 1) * 64;
    const int wn   = (w & 1) * 64;

    const int nwg = gridDim.x * gridDim.y;
    const int cpx = nwg >> 3;
    int id = blockIdx.y * gridDim.x + blockIdx.x;
    id = (id & 7) * cpx + (id >> 3);
    const int tileN = (id % 8) * 128;      // gridDim.x == 8
    const int tileM = (id / 8) * 128;

    const f32x4 vzero = {0.f, 0.f, 0.f, 0.f};
    f32x4 acc[4][4];
#pragma unroll
    for (int i = 0; i < 4; i++)
#pragma unroll
        for (int j = 0; j < 4; j++) acc[i][j] = vzero;

    const int par4 = (l15 & 1) << 2;

    for (int k0 = 0; k0 < K; k0 += 64) {
        __syncthreads();
#pragma unroll
        for (int q = 0; q < 4; q++) {
            const int r0 = w * 32 + q * 8;
            stage8(&A[(size_t)(tileM + r0) * K + k0], K, &As[r0 * 64], lane);
            stage8(&Bm[(size_t)(tileN + r0) * K + k0], K, &Bs[r0 * 64], lane);
        }
        __syncthreads();

#pragma unroll
        for (int ss = 0; ss < 2; ss++) {
            const int phys = ((ss * 4 + quad) ^ par4) << 3;
            bf16x8 af[4], bf[4];
#pragma unroll
            for (int i = 0; i < 4; i++)
                af[i] = *(bf16x8*)&As[(wm + i * 16 + l15) * 64 + phys];
#pragma unroll
            for (int j = 0; j < 4; j++)
                bf[j] = *(bf16x8*)&Bs[(wn + j * 16 + l15) * 64 + phys];
#pragma unroll
            for (int i = 0; i < 4; i++)
#pragma unroll
                for (int j = 0; j < 4; j++)
                    acc[i][j] = __builtin_amdgcn_mfma_f32_16x16x32_bf16(
                        af[i], bf[j], acc[i][j], 0, 0, 0);
        }
    }

#pragma unroll
    for (int i = 0; i < 4; i++) {
#pragma unroll
        for (int r = 0; r < 4; r++) {
            const int row = tileM + wm + i * 16 + quad * 4 + r;
#pragma unroll
            for (int j = 0; j < 4; j++)
                C[(size_t)row * N + tileN + wn + j * 16 + l15] = acc[i][j][r];
        }
    }
}

// ---------------------------------------------------------------------------
// Flash causal attention v9: v8 (T14 reg prefetch + LDS dbuf + setprio)
// with the softmax scale now PRE-FOLDED into Q by gemm_qkv -> exp2 input
// is the raw MFMA output (32 fewer VALU muls/lane/tile; attn is
// VALU/softmax-bound: VALUBusy 37%, MfmaUtil 21).
// Single __syncthreads per key-tile (dbuf parity: nkt always even).
// Grid (nbh, 8): block handles strips sp and 15-sp (34 key-tiles, uniform);
// linear id mod 8 keeps each (b,h)'s K/V slab XCD-local.
// No-max softmax; Ps chunk-swizzled; row-sums via ones-MFMA; Y aliases Q.
// ---------------------------------------------------------------------------
__global__ __launch_bounds__(256, 2) void attn_causal(
    const bf16_t* __restrict__ Q, const bf16_t* __restrict__ Kg,
    const bf16_t* __restrict__ Vt_g, bf16_t* __restrict__ Y)
{
    __shared__ alignas(16) bf16_t Ks[2 * 64 * 72];  // [buf][key][d]
    __shared__ alignas(16) bf16_t Vt[2 * 64 * 72];  // [buf][d][key]
    __shared__ alignas(16) bf16_t Ps[4][32 * 72];   // per-wave P, chunk-swizzled

    const int tid  = threadIdx.x;
    const int lane = tid & 63;
    const int w    = tid >> 6;
    const int quad = lane >> 4;
    const int l15  = lane & 15;
    const int bh   = blockIdx.x;
    const int sp   = blockIdx.y;         // 0..7
    const int b = bh >> 4, h = bh & 15;

    const int stg_row = tid >> 3;        // 0..31
    const int stg_c8  = (tid & 7) * 8;
    const int stg_off = stg_row * 72 + stg_c8;

    const f32x4 vzero = {0.f, 0.f, 0.f, 0.f};
    bf16x8 ones;
#pragma unroll
    for (int j = 0; j < 8; j++) ones[j] = (l15 == 0) ? (bf16_t)1.0f : (bf16_t)0.0f;

    // kt-invariant per-thread staging addresses
    const bf16_t* kg0 = &Kg[(size_t)(b * TT + stg_row) * DDIM + h * 64 + stg_c8];
    const bf16_t* vg0 = &Vt_g[((size_t)bh * HD + stg_row) * TT + stg_c8];

#pragma unroll 1
    for (int half = 0; half < 2; half++) {
        const int strip = half ? (15 - sp) : sp;   // 0..15, 128 rows
        const int qbase = strip * 128;

        bf16x8 qf[2][2];
#pragma unroll
        for (int mi = 0; mi < 2; mi++) {
            const size_t rq =
                (size_t)(b * TT + qbase + w * 32 + mi * 16 + l15) * DDIM + h * 64;
            qf[mi][0] = *(const bf16x8*)&Q[rq + quad * 8];
            qf[mi][1] = *(const bf16x8*)&Q[rq + 32 + quad * 8];
        }

        f32x4 o[2][4], o4[2];
#pragma unroll
        for (int mi = 0; mi < 2; mi++) {
#pragma unroll
            for (int c = 0; c < 4; c++) o[mi][c] = vzero;
            o4[mi] = vzero;
        }

        const int nkt = 2 * strip + 2;   // always even

        // T14 prologue: prefetch key-tile 0 into registers
        bf16x8 kreg[2], vreg[2];
#pragma unroll
        for (int p = 0; p < 2; p++) {
            kreg[p] = *(const bf16x8*)&kg0[(size_t)(p * 32) * DDIM];
            vreg[p] = *(const bf16x8*)&vg0[(size_t)(p * 32) * TT];
        }

#pragma unroll 1
        for (int kt = 0; kt < nkt; kt++) {
            const int kbase = kt * 64;
            const int coff = (kt & 1) * (64 * 72);
            // retire prefetched regs into buf[kt&1] (race-free: see header)
#pragma unroll
            for (int p = 0; p < 2; p++) {
                *(bf16x8*)&Ks[coff + stg_off + p * 32 * 72] = kreg[p];
                *(bf16x8*)&Vt[coff + stg_off + p * 32 * 72] = vreg[p];
            }
            // issue next tile's global loads; latency hides under compute
            if (kt + 1 < nkt) {
                const int nb = (kt + 1) * 64;
#pragma unroll
                for (int p = 0; p < 2; p++) {
                    kreg[p] = *(const bf16x8*)&kg0[(size_t)(nb + p * 32) * DDIM];
                    vreg[p] = *(const bf16x8*)&vg0[(size_t)(p * 32) * TT + nb];
                }
            }
            __syncthreads();             // single barrier per key-tile

            // S = Q·K^T : shared kf reads across both m-fragments
            f32x4 s[2][4];
            __builtin_amdgcn_s_setprio(1);
#pragma unroll
            for (int c = 0; c < 4; c++) {
                bf16x8 kf0 = *(bf16x8*)&Ks[coff + (c * 16 + l15) * 72 + quad * 8];
                bf16x8 kf1 = *(bf16x8*)&Ks[coff + (c * 16 + l15) * 72 + 32 + quad * 8];
#pragma unroll
                for (int mi = 0; mi < 2; mi++) {
                    f32x4 t = __builtin_amdgcn_mfma_f32_16x16x32_bf16(
                        qf[mi][0], kf0, vzero, 0, 0, 0);
                    s[mi][c] = __builtin_amdgcn_mfma_f32_16x16x32_bf16(
                        qf[mi][1], kf1, t, 0, 0, 0);
                }
            }
            __builtin_amdgcn_s_setprio(0);

            // p = exp2(s) (scale pre-folded into Q); mask near the diagonal
#pragma unroll
            for (int mi = 0; mi < 2; mi++) {
                const int qlow = qbase + w * 32 + mi * 16;
                const bool need = (kbase + 63 > qlow);   // wave-uniform
#pragma unroll
                for (int r = 0; r < 4; r++) {
                    const int qrow = qlow + quad * 4 + r;
                    const int prow = mi * 16 + quad * 4 + r;
#pragma unroll
                    for (int c = 0; c < 4; c++) {
                        float sv = s[mi][c][r];
                        if (need && (kbase + c * 16 + l15 > qrow)) sv = -1e30f;
                        const int pchunk = (c * 2 + (l15 >> 3)) ^ (prow >> 2);
                        Ps[w][prow * 72 + (pchunk << 3) + (l15 & 7)] =
                            (bf16_t)__builtin_amdgcn_exp2f(sv);
                    }
                }
            }
            // Ps wave-private: same-wave RAW via lgkmcnt, no barrier.

            // O += P·V ; o4 += P·ones
            __builtin_amdgcn_s_setprio(1);
#pragma unroll
            for (int ss = 0; ss < 2; ss++) {
                bf16x8 pf[2];
#pragma unroll
                for (int mi = 0; mi < 2; mi++) {
                    const int m = mi * 16 + l15;
                    pf[mi] = *(bf16x8*)&Ps[w][m * 72 +
                                              ((((ss * 4 + quad) ^ (m >> 2)) & 7) << 3)];
                }
#pragma unroll
                for (int c = 0; c < 4; c++) {
                    bf16x8 vf = *(bf16x8*)&Vt[coff + (c * 16 + l15) * 72 + ss * 32 + quad * 8];
#pragma unroll
                    for (int mi = 0; mi < 2; mi++)
                        o[mi][c] = __builtin_amdgcn_mfma_f32_16x16x32_bf16(
                            pf[mi], vf, o[mi][c], 0, 0, 0);
                }
#pragma unroll
                for (int mi = 0; mi < 2; mi++)
                    o4[mi] = __builtin_amdgcn_mfma_f32_16x16x32_bf16(
                        pf[mi], ones, o4[mi], 0, 0, 0);
            }
            __builtin_amdgcn_s_setprio(0);
        }

        // epilogue: row-sum lives in lane l15==0 of each quad group
#pragma unroll
        for (int mi = 0; mi < 2; mi++) {
#pragma unroll
            for (int r = 0; r < 4; r++) {
                const float lsum = __shfl(o4[mi][r], lane & 48, 64);
                const float inv = 1.0f / lsum;
                const int q = qbase + w * 32 + mi * 16 + quad * 4 + r;
#pragma unroll
                for (int c = 0; c < 4; c++)
                    Y[(size_t)(b * TT + q) * DDIM + h * 64 + c * 16 + l15] =
                        (bf16_t)(o[mi][c][r] * inv);
            }
        }
    }
}

extern "C" void kernel_launch(void* const* d_in, const int* in_sizes, int n_in,
                              void* d_out, int out_size, void* d_ws, size_t ws_size,
                              hipStream_t stream) {
    (void)in_sizes; (void)n_in; (void)out_size;
    const float* x  = (const float*)d_in[0];
    float* out = (float*)d_out;

    const int M = BB * TT;                     // 8192
    const size_t REGION = (size_t)M * DDIM;    // 8M elems
    const size_t WREG   = (size_t)DDIM * DDIM; // 1M elems
    const size_t BATCH  = (size_t)TT * DDIM;   // 2M elems
    bf16_t* ws = (bf16_t*)d_ws;

    if (ws_size >= (72ull << 20)) {
        // Full path: xb(8M) wpk(4M) Qb(8M) Kb(8M) Vtb(8M) = 36M bf16 = 72 MiB.
        bf16_t* xb  = ws;
        bf16_t* wpk = ws + REGION;
        bf16_t* Qb  = wpk + 4 * WREG;
        bf16_t* Kb  = Qb + REGION;
        bf16_t* Vtb = Kb + REGION;

        cvt_f32_bf16<<<1024, 256, 0, stream>>>(x, xb, REGION / 8);
        cvt_wpack<<<512, 256, 0, stream>>>(
            (const float*)d_in[1], (const float*)d_in[2],
            (const float*)d_in[3], (const float*)d_in[4], wpk);

        gemm_qkv<<<dim3(24, M / 128), 256, 0, stream>>>(
            xb, wpk, Qb, Kb, Vtb, M, DDIM);
        attn_causal<<<dim3(BB * HH, 8), 256, 0, stream>>>(Qb, Kb, Vtb, Qb);
        gemm_out<<<dim3(8, M / 128), 256, 0, stream>>>(
            Qb, wpk + 3 * WREG, out, M, DDIM, DDIM);
    } else {
        // Per-batch path: wpk(4M) + xb(2M) + Qb,Kb,Vtb(3x2M) = 12M = 24 MiB.
        bf16_t* wpk = ws;
        bf16_t* xbb = ws + 4 * WREG;
        bf16_t* Qb  = xbb + BATCH;
        bf16_t* Kb  = Qb + BATCH;
        bf16_t* Vtb = Kb + BATCH;

        cvt_wpack<<<512, 256, 0, stream>>>(
            (const float*)d_in[1], (const float*)d_in[2],
            (const float*)d_in[3], (const float*)d_in[4], wpk);

        for (int b = 0; b < BB; b++) {
            const float* x_b = x + (size_t)b * BATCH;
            float* out_b = out + (size_t)b * BATCH;
            cvt_f32_bf16<<<512, 256, 0, stream>>>(x_b, xbb, BATCH / 8);
            gemm_qkv<<<dim3(24, TT / 128), 256, 0, stream>>>(
                xbb, wpk, Qb, Kb, Vtb, TT, DDIM);
            attn_causal<<<dim3(HH, 8), 256, 0, stream>>>(Qb, Kb, Vtb, Qb);
            gemm_out<<<dim3(8, TT / 128), 256, 0, stream>>>(
                Qb, wpk + 3 * WREG, out_b, TT, DDIM, DDIM);
        }
    }
}

// Round 5
// 244.816 us; speedup vs baseline: 1.2072x; 1.0392x over previous
//
#include <hip/hip_runtime.h>
#include <hip/hip_bf16.h>

#define BB 4
#define TT 2048
#define DDIM 1024
#define HH 16
#define HD 64

typedef __bf16 bf16_t;
typedef __bf16 bf16x4 __attribute__((ext_vector_type(4)));
typedef __bf16 bf16x8 __attribute__((ext_vector_type(8)));
typedef float f32x4 __attribute__((ext_vector_type(4)));

#define GLOAD_LDS(gp, lp) \
    __builtin_amdgcn_global_load_lds( \
        (const __attribute__((address_space(1))) void*)(gp), \
        (__attribute__((address_space(3))) void*)(lp), 16, 0, 0)

// ---------------------------------------------------------------------------
// fp32 -> bf16 conversion, 8 elems/thread, grid-stride. n8 = n/8.
// ---------------------------------------------------------------------------
__global__ __launch_bounds__(256) void cvt_f32_bf16(
    const float* __restrict__ src, bf16_t* __restrict__ dst, size_t n8)
{
    size_t i = (size_t)blockIdx.x * blockDim.x + threadIdx.x;
    const size_t stride = (size_t)gridDim.x * blockDim.x;
    for (; i < n8; i += stride) {
        const f32x4 a = ((const f32x4*)src)[2 * i];
        const f32x4 b = ((const f32x4*)src)[2 * i + 1];
        bf16x8 v;
#pragma unroll
        for (int j = 0; j < 4; j++) { v[j] = (bf16_t)a[j]; v[4 + j] = (bf16_t)b[j]; }
        ((bf16x8*)dst)[i] = v;
    }
}

// Pack 4 fp32 weight matrices into one bf16 buffer [wq|wk|wv|wo].
__global__ __launch_bounds__(256) void cvt_wpack(
    const float* __restrict__ s0, const float* __restrict__ s1,
    const float* __restrict__ s2, const float* __restrict__ s3,
    bf16_t* __restrict__ dst)
{
    const size_t n8 = (size_t)4 * DDIM * DDIM / 8;
    size_t i = (size_t)blockIdx.x * blockDim.x + threadIdx.x;
    const size_t stride = (size_t)gridDim.x * blockDim.x;
    for (; i < n8; i += stride) {
        const int sel = (int)(i >> 17);
        const float* s = sel == 0 ? s0 : sel == 1 ? s1 : sel == 2 ? s2 : s3;
        const size_t off8 = i & ((1u << 17) - 1);
        const f32x4 a = ((const f32x4*)s)[2 * off8];
        const f32x4 b = ((const f32x4*)s)[2 * off8 + 1];
        bf16x8 v;
#pragma unroll
        for (int j = 0; j < 4; j++) { v[j] = (bf16_t)a[j]; v[4 + j] = (bf16_t)b[j]; }
        ((bf16x8*)dst)[i] = v;
    }
}

// ---------------------------------------------------------------------------
// BK=64 FULL-row XOR staging. global_load_lds writes linearly (base +
// lane*16B), so the GLOBAL source chunk is pre-permuted: LDS(row, j) =
// G(row, j ^ (row&7)) at 8-elem chunk granularity. Reads un-XOR with
// (row&7) == (l15&7) on every fragment row -> every 16-lane quarter-phase
// covers all 8 16B slots exactly twice (bandwidth-minimal; the previous
// row&1 XOR left 8-way aliasing: SQ_LDS_BANK_CONFLICT 1.9e7/dispatch).
// Stages 8 rows per instruction: lane -> row lane>>3, chunk lane&7.
// ---------------------------------------------------------------------------
__device__ __forceinline__ void stage8(const bf16_t* __restrict__ g, int ld,
                                       bf16_t* __restrict__ ldsbase, int lane)
{
    const int rr = lane >> 3;
    const int cc = (lane & 7) ^ rr;
    GLOAD_LDS(&g[(size_t)rr * ld + cc * 8], ldsbase);
}

// ---------------------------------------------------------------------------
// Fused QKV GEMM v4: 128x128 tile, BK=64, 2-phase double-buffer.
// Per tile t: issue ALL of tile t+1's global_load_lds into buf^1 FIRST,
// then ds_read+32 MFMA on buf[cur], then ONE __syncthreads (its vmcnt/lgkm
// drain lands after ~32 MFMA of cover instead of naked). LDS 64 KiB ->
// 2 blocks/CU retained (round-2's failed variant had intra-tile lockstep
// barriers at 1 blk/CU -- not repeated here).
// Full-row XOR swizzle (see stage8) removes the 8-way read aliasing.
// T1 XCD swizzle; Q-region epilogue pre-scales by 0.125*log2e.
// ---------------------------------------------------------------------------
__global__ __launch_bounds__(256) void gemm_qkv(
    const bf16_t* __restrict__ A, const bf16_t* __restrict__ Wqkv,
    bf16_t* __restrict__ Qo, bf16_t* __restrict__ Ko, bf16_t* __restrict__ Vto,
    int M, int K)
{
    __shared__ alignas(16) bf16_t As[2][128 * 64];
    __shared__ alignas(16) bf16_t Bs[2][128 * 64];

    const int tid  = threadIdx.x;
    const int lane = tid & 63;
    const int w    = tid >> 6;
    const int quad = lane >> 4;
    const int l15  = lane & 15;
    const int wm   = (w >> 1) * 64;
    const int wn   = (w & 1) * 64;

    // T1 XCD swizzle: hw linear id -> contiguous chunk per XCD
    const int nwg = gridDim.x * gridDim.y;
    const int cpx = nwg >> 3;
    int id = blockIdx.y * gridDim.x + blockIdx.x;
    id = (id & 7) * cpx + (id >> 3);
    const int tileN = (id % 24) * 128;     // gridDim.x == 24 in both paths
    const int tileM = (id / 24) * 128;

    const f32x4 vzero = {0.f, 0.f, 0.f, 0.f};
    f32x4 acc[4][4];
#pragma unroll
    for (int i = 0; i < 4; i++)
#pragma unroll
        for (int j = 0; j < 4; j++) acc[i][j] = vzero;

    const int par8 = l15 & 7;            // read-side un-XOR (row&7 == l15&7)

    // prologue: stage K-tile 0 into buf 0
#pragma unroll
    for (int q = 0; q < 4; q++) {
        const int r0 = w * 32 + q * 8;
        stage8(&A[(size_t)(tileM + r0) * K], K, &As[0][r0 * 64], lane);
        stage8(&Wqkv[(size_t)(tileN + r0) * K], K, &Bs[0][r0 * 64], lane);
    }
    __syncthreads();

    const int NT = K >> 6;
    for (int t = 0; t < NT; ++t) {
        const int cur = t & 1;
        if (t + 1 < NT) {                // issue next tile's loads first
            const int k0 = (t + 1) << 6;
#pragma unroll
            for (int q = 0; q < 4; q++) {
                const int r0 = w * 32 + q * 8;
                stage8(&A[(size_t)(tileM + r0) * K + k0], K,
                       &As[cur ^ 1][r0 * 64], lane);
                stage8(&Wqkv[(size_t)(tileN + r0) * K + k0], K,
                       &Bs[cur ^ 1][r0 * 64], lane);
            }
        }

#pragma unroll
        for (int ss = 0; ss < 2; ss++) {
            const int phys = ((ss * 4 + quad) ^ par8) << 3;
            bf16x8 af[4], bf[4];
#pragma unroll
            for (int i = 0; i < 4; i++)
                af[i] = *(bf16x8*)&As[cur][(wm + i * 16 + l15) * 64 + phys];
#pragma unroll
            for (int j = 0; j < 4; j++)
                bf[j] = *(bf16x8*)&Bs[cur][(wn + j * 16 + l15) * 64 + phys];
            __builtin_amdgcn_s_setprio(1);
#pragma unroll
            for (int i = 0; i < 4; i++)
#pragma unroll
                for (int j = 0; j < 4; j++)
                    acc[i][j] = __builtin_amdgcn_mfma_f32_16x16x32_bf16(
                        af[i], bf[j], acc[i][j], 0, 0, 0);
            __builtin_amdgcn_s_setprio(0);
        }
        __syncthreads();   // drains this wave's stage; buf^1 complete for t+1
    }

    const int region = tileN >> 10;    // 0=Q, 1=K, 2=V (block-uniform)
    const float osc = (region == 0) ? 0.125f * 1.44269504f : 1.0f;
#pragma unroll
    for (int i = 0; i < 4; i++) {
        const int row = tileM + wm + i * 16 + quad * 4;
#pragma unroll
        for (int j = 0; j < 4; j++) {
            const int ncol = tileN + wn + j * 16 + l15;
            if (region == 2) {
                const int cl = ncol - 2048;
                const int h = cl >> 6, d = cl & 63;
                const int bb = row >> 11, tloc = row & (TT - 1);
                bf16x4 pk;
#pragma unroll
                for (int r = 0; r < 4; r++) pk[r] = (bf16_t)acc[i][j][r];
                *(bf16x4*)&Vto[(((size_t)bb * HH + h) * HD + d) * TT + tloc] = pk;
            } else {
                bf16_t* dst = (region == 0) ? Qo : Ko;
                const int cl = ncol & 1023;
#pragma unroll
                for (int r = 0; r < 4; r++)
                    dst[(size_t)(row + r) * DDIM + cl] = (bf16_t)(acc[i][j][r] * osc);
            }
        }
    }
}

// ---------------------------------------------------------------------------
// Output-projection GEMM v3: 128x128 tile, 2-phase double-buffer, full-row
// XOR swizzle (same structure as gemm_qkv), fp32 epilogue. Grid (8, M/128).
// ---------------------------------------------------------------------------
__global__ __launch_bounds__(256) void gemm_out(
    const bf16_t* __restrict__ A, const bf16_t* __restrict__ Bm,
    float* __restrict__ C, int M, int N, int K)
{
    __shared__ alignas(16) bf16_t As[2][128 * 64];
    __shared__ alignas(16) bf16_t Bs[2][128 * 64];

    const int tid  = threadIdx.x;
    const int lane = tid & 63;
    const int w    = tid >> 6;
    const int quad = lane >> 4;
    const int l15  = lane & 15;
    const int wm   = (w >> 1) * 64;
    const int wn   = (w & 1) * 64;

    const int nwg = gridDim.x * gridDim.y;
    const int cpx = nwg >> 3;
    int id = blockIdx.y * gridDim.x + blockIdx.x;
    id = (id & 7) * cpx + (id >> 3);
    const int tileN = (id % 8) * 128;      // gridDim.x == 8
    const int tileM = (id / 8) * 128;

    const f32x4 vzero = {0.f, 0.f, 0.f, 0.f};
    f32x4 acc[4][4];
#pragma unroll
    for (int i = 0; i < 4; i++)
#pragma unroll
        for (int j = 0; j < 4; j++) acc[i][j] = vzero;

    const int par8 = l15 & 7;

#pragma unroll
    for (int q = 0; q < 4; q++) {
        const int r0 = w * 32 + q * 8;
        stage8(&A[(size_t)(tileM + r0) * K], K, &As[0][r0 * 64], lane);
        stage8(&Bm[(size_t)(tileN + r0) * K], K, &Bs[0][r0 * 64], lane);
    }
    __syncthreads();

    const int NT = K >> 6;
    for (int t = 0; t < NT; ++t) {
        const int cur = t & 1;
        if (t + 1 < NT) {
            const int k0 = (t + 1) << 6;
#pragma unroll
            for (int q = 0; q < 4; q++) {
                const int r0 = w * 32 + q * 8;
                stage8(&A[(size_t)(tileM + r0) * K + k0], K,
                       &As[cur ^ 1][r0 * 64], lane);
                stage8(&Bm[(size_t)(tileN + r0) * K + k0], K,
                       &Bs[cur ^ 1][r0 * 64], lane);
            }
        }

#pragma unroll
        for (int ss = 0; ss < 2; ss++) {
            const int phys = ((ss * 4 + quad) ^ par8) << 3;
            bf16x8 af[4], bf[4];
#pragma unroll
            for (int i = 0; i < 4; i++)
                af[i] = *(bf16x8*)&As[cur][(wm + i * 16 + l15) * 64 + phys];
#pragma unroll
            for (int j = 0; j < 4; j++)
                bf[j] = *(bf16x8*)&Bs[cur][(wn + j * 16 + l15) * 64 + phys];
            __builtin_amdgcn_s_setprio(1);
#pragma unroll
            for (int i = 0; i < 4; i++)
#pragma unroll
                for (int j = 0; j < 4; j++)
                    acc[i][j] = __builtin_amdgcn_mfma_f32_16x16x32_bf16(
                        af[i], bf[j], acc[i][j], 0, 0, 0);
            __builtin_amdgcn_s_setprio(0);
        }
        __syncthreads();
    }

#pragma unroll
    for (int i = 0; i < 4; i++) {
#pragma unroll
        for (int r = 0; r < 4; r++) {
            const int row = tileM + wm + i * 16 + quad * 4 + r;
#pragma unroll
            for (int j = 0; j < 4; j++)
                C[(size_t)row * N + tileN + wn + j * 16 + l15] = acc[i][j][r];
        }
    }
}

// ---------------------------------------------------------------------------
// Flash causal attention v10: v9 + Ks/Vt moved from stride-72 to stride-64
// with full row&7 chunk-XOR (reg-staged, so LDS-side XOR is free; all
// fragment-read rows have row&7 == l15&7 -> reads un-XOR cleanly and every
// quarter-phase covers all 8 slots twice = conflict-free). LDS 54 -> 50 KiB
// -> 3 blocks/CU (12 waves, +50% TLP against the ~40% idle fraction).
// Single __syncthreads per key-tile (dbuf parity: nkt always even).
// Scale pre-folded into Q by gemm_qkv -> exp2 input is raw MFMA output.
// Grid (nbh, 8): block handles strips sp and 15-sp (34 key-tiles, uniform);
// linear id mod 8 keeps each (b,h)'s K/V slab XCD-local.
// No-max softmax; Ps chunk-swizzled (stride 72, natural rotation -> free);
// row-sums via ones-MFMA; Y aliases Q.
// ---------------------------------------------------------------------------
__global__ __launch_bounds__(256, 3) void attn_causal(
    const bf16_t* __restrict__ Q, const bf16_t* __restrict__ Kg,
    const bf16_t* __restrict__ Vt_g, bf16_t* __restrict__ Y)
{
    __shared__ alignas(16) bf16_t Ks[2 * 64 * 64];  // [buf][key][d] XOR-swz
    __shared__ alignas(16) bf16_t Vt[2 * 64 * 64];  // [buf][d][key] XOR-swz
    __shared__ alignas(16) bf16_t Ps[4][32 * 72];   // per-wave P, chunk-swz

    const int tid  = threadIdx.x;
    const int lane = tid & 63;
    const int w    = tid >> 6;
    const int quad = lane >> 4;
    const int l15  = lane & 15;
    const int bh   = blockIdx.x;
    const int sp   = blockIdx.y;         // 0..7
    const int b = bh >> 4, h = bh & 15;

    const int stg_row = tid >> 3;        // 0..31
    const int stg_c8  = (tid & 7) * 8;
    // LDS write offset with full-row XOR at 8-elem chunk granularity
    const int stg_off = stg_row * 64 + ((((tid & 7) ^ (stg_row & 7))) << 3);
    const int par8 = l15 & 7;            // read-side un-XOR

    const f32x4 vzero = {0.f, 0.f, 0.f, 0.f};
    bf16x8 ones;
#pragma unroll
    for (int j = 0; j < 8; j++) ones[j] = (l15 == 0) ? (bf16_t)1.0f : (bf16_t)0.0f;

    // kt-invariant per-thread staging addresses (global side unchanged)
    const bf16_t* kg0 = &Kg[(size_t)(b * TT + stg_row) * DDIM + h * 64 + stg_c8];
    const bf16_t* vg0 = &Vt_g[((size_t)bh * HD + stg_row) * TT + stg_c8];

#pragma unroll 1
    for (int half = 0; half < 2; half++) {
        const int strip = half ? (15 - sp) : sp;   // 0..15, 128 rows
        const int qbase = strip * 128;

        bf16x8 qf[2][2];
#pragma unroll
        for (int mi = 0; mi < 2; mi++) {
            const size_t rq =
                (size_t)(b * TT + qbase + w * 32 + mi * 16 + l15) * DDIM + h * 64;
            qf[mi][0] = *(const bf16x8*)&Q[rq + quad * 8];
            qf[mi][1] = *(const bf16x8*)&Q[rq + 32 + quad * 8];
        }

        f32x4 o[2][4], o4[2];
#pragma unroll
        for (int mi = 0; mi < 2; mi++) {
#pragma unroll
            for (int c = 0; c < 4; c++) o[mi][c] = vzero;
            o4[mi] = vzero;
        }

        const int nkt = 2 * strip + 2;   // always even

        // T14 prologue: prefetch key-tile 0 into registers
        bf16x8 kreg[2], vreg[2];
#pragma unroll
        for (int p = 0; p < 2; p++) {
            kreg[p] = *(const bf16x8*)&kg0[(size_t)(p * 32) * DDIM];
            vreg[p] = *(const bf16x8*)&vg0[(size_t)(p * 32) * TT];
        }

#pragma unroll 1
        for (int kt = 0; kt < nkt; kt++) {
            const int kbase = kt * 64;
            const int coff = (kt & 1) * (64 * 64);
            // retire prefetched regs into buf[kt&1] (race-free: see header)
#pragma unroll
            for (int p = 0; p < 2; p++) {
                *(bf16x8*)&Ks[coff + stg_off + p * 32 * 64] = kreg[p];
                *(bf16x8*)&Vt[coff + stg_off + p * 32 * 64] = vreg[p];
            }
            // issue next tile's global loads; latency hides under compute
            if (kt + 1 < nkt) {
                const int nb = (kt + 1) * 64;
#pragma unroll
                for (int p = 0; p < 2; p++) {
                    kreg[p] = *(const bf16x8*)&kg0[(size_t)(nb + p * 32) * DDIM];
                    vreg[p] = *(const bf16x8*)&vg0[(size_t)(p * 32) * TT + nb];
                }
            }
            __syncthreads();             // single barrier per key-tile

            // S = Q·K^T : shared kf reads across both m-fragments
            f32x4 s[2][4];
            __builtin_amdgcn_s_setprio(1);
#pragma unroll
            for (int c = 0; c < 4; c++) {
                const int krow = (c * 16 + l15) * 64;
                bf16x8 kf0 = *(bf16x8*)&Ks[coff + krow + ((quad ^ par8) << 3)];
                bf16x8 kf1 = *(bf16x8*)&Ks[coff + krow + (((4 + quad) ^ par8) << 3)];
#pragma unroll
                for (int mi = 0; mi < 2; mi++) {
                    f32x4 t = __builtin_amdgcn_mfma_f32_16x16x32_bf16(
                        qf[mi][0], kf0, vzero, 0, 0, 0);
                    s[mi][c] = __builtin_amdgcn_mfma_f32_16x16x32_bf16(
                        qf[mi][1], kf1, t, 0, 0, 0);
                }
            }
            __builtin_amdgcn_s_setprio(0);

            // p = exp2(s) (scale pre-folded into Q); mask near the diagonal
#pragma unroll
            for (int mi = 0; mi < 2; mi++) {
                const int qlow = qbase + w * 32 + mi * 16;
                const bool need = (kbase + 63 > qlow);   // wave-uniform
#pragma unroll
                for (int r = 0; r < 4; r++) {
                    const int qrow = qlow + quad * 4 + r;
                    const int prow = mi * 16 + quad * 4 + r;
#pragma unroll
                    for (int c = 0; c < 4; c++) {
                        float sv = s[mi][c][r];
                        if (need && (kbase + c * 16 + l15 > qrow)) sv = -1e30f;
                        const int pchunk = (c * 2 + (l15 >> 3)) ^ (prow >> 2);
                        Ps[w][prow * 72 + (pchunk << 3) + (l15 & 7)] =
                            (bf16_t)__builtin_amdgcn_exp2f(sv);
                    }
                }
            }
            // Ps wave-private: same-wave RAW via lgkmcnt, no barrier.

            // O += P·V ; o4 += P·ones
            __builtin_amdgcn_s_setprio(1);
#pragma unroll
            for (int ss = 0; ss < 2; ss++) {
                bf16x8 pf[2];
#pragma unroll
                for (int mi = 0; mi < 2; mi++) {
                    const int m = mi * 16 + l15;
                    pf[mi] = *(bf16x8*)&Ps[w][m * 72 +
                                              ((((ss * 4 + quad) ^ (m >> 2)) & 7) << 3)];
                }
#pragma unroll
                for (int c = 0; c < 4; c++) {
                    bf16x8 vf = *(bf16x8*)&Vt[coff + (c * 16 + l15) * 64 +
                                              (((ss * 4 + quad) ^ par8) << 3)];
#pragma unroll
                    for (int mi = 0; mi < 2; mi++)
                        o[mi][c] = __builtin_amdgcn_mfma_f32_16x16x32_bf16(
                            pf[mi], vf, o[mi][c], 0, 0, 0);
                }
#pragma unroll
                for (int mi = 0; mi < 2; mi++)
                    o4[mi] = __builtin_amdgcn_mfma_f32_16x16x32_bf16(
                        pf[mi], ones, o4[mi], 0, 0, 0);
            }
            __builtin_amdgcn_s_setprio(0);
        }

        // epilogue: row-sum lives in lane l15==0 of each quad group
#pragma unroll
        for (int mi = 0; mi < 2; mi++) {
#pragma unroll
            for (int r = 0; r < 4; r++) {
                const float lsum = __shfl(o4[mi][r], lane & 48, 64);
                const float inv = 1.0f / lsum;
                const int q = qbase + w * 32 + mi * 16 + quad * 4 + r;
#pragma unroll
                for (int c = 0; c < 4; c++)
                    Y[(size_t)(b * TT + q) * DDIM + h * 64 + c * 16 + l15] =
                        (bf16_t)(o[mi][c][r] * inv);
            }
        }
    }
}

extern "C" void kernel_launch(void* const* d_in, const int* in_sizes, int n_in,
                              void* d_out, int out_size, void* d_ws, size_t ws_size,
                              hipStream_t stream) {
    (void)in_sizes; (void)n_in; (void)out_size;
    const float* x  = (const float*)d_in[0];
    float* out = (float*)d_out;

    const int M = BB * TT;                     // 8192
    const size_t REGION = (size_t)M * DDIM;    // 8M elems
    const size_t WREG   = (size_t)DDIM * DDIM; // 1M elems
    const size_t BATCH  = (size_t)TT * DDIM;   // 2M elems
    bf16_t* ws = (bf16_t*)d_ws;

    if (ws_size >= (72ull << 20)) {
        // Full path: xb(8M) wpk(4M) Qb(8M) Kb(8M) Vtb(8M) = 36M bf16 = 72 MiB.
        bf16_t* xb  = ws;
        bf16_t* wpk = ws + REGION;
        bf16_t* Qb  = wpk + 4 * WREG;
        bf16_t* Kb  = Qb + REGION;
        bf16_t* Vtb = Kb + REGION;

        cvt_f32_bf16<<<1024, 256, 0, stream>>>(x, xb, REGION / 8);
        cvt_wpack<<<512, 256, 0, stream>>>(
            (const float*)d_in[1], (const float*)d_in[2],
            (const float*)d_in[3], (const float*)d_in[4], wpk);

        gemm_qkv<<<dim3(24, M / 128), 256, 0, stream>>>(
            xb, wpk, Qb, Kb, Vtb, M, DDIM);
        attn_causal<<<dim3(BB * HH, 8), 256, 0, stream>>>(Qb, Kb, Vtb, Qb);
        gemm_out<<<dim3(8, M / 128), 256, 0, stream>>>(
            Qb, wpk + 3 * WREG, out, M, DDIM, DDIM);
    } else {
        // Per-batch path: wpk(4M) + xb(2M) + Qb,Kb,Vtb(3x2M) = 12M = 24 MiB.
        bf16_t* wpk = ws;
        bf16_t* xbb = ws + 4 * WREG;
        bf16_t* Qb  = xbb + BATCH;
        bf16_t* Kb  = Qb + BATCH;
        bf16_t* Vtb = Kb + BATCH;

        cvt_wpack<<<512, 256, 0, stream>>>(
            (const float*)d_in[1], (const float*)d_in[2],
            (const float*)d_in[3], (const float*)d_in[4], wpk);

        for (int b = 0; b < BB; b++) {
            const float* x_b = x + (size_t)b * BATCH;
            float* out_b = out + (size_t)b * BATCH;
            cvt_f32_bf16<<<512, 256, 0, stream>>>(x_b, xbb, BATCH / 8);
            gemm_qkv<<<dim3(24, TT / 128), 256, 0, stream>>>(
                xbb, wpk, Qb, Kb, Vtb, TT, DDIM);
            attn_causal<<<dim3(HH, 8), 256, 0, stream>>>(Qb, Kb, Vtb, Qb);
            gemm_out<<<dim3(8, TT / 128), 256, 0, stream>>>(
                Qb, wpk + 3 * WREG, out_b, TT, DDIM, DDIM);
        }
    }
}